// Round 9
// baseline (204.472 us; speedup 1.0000x reference)
//
#include <hip/hip_runtime.h>
#include <hip/hip_bf16.h>
#include <math.h>

#define NROWS 32768
#define DD    1024
#define EE    640
#define VV    320
#define BM    128
#define KT    32      // DD/32
#define CTN   40      // EE/16

typedef __attribute__((ext_vector_type(8))) short short8;
typedef __attribute__((ext_vector_type(4))) short short4v;
typedef __attribute__((ext_vector_type(4))) float float4v;

static __device__ __forceinline__ unsigned short f2bf(float f) {
    unsigned int u = __float_as_uint(f);
    return (unsigned short)((u + 0x7fffu + ((u >> 16) & 1u)) >> 16); // RNE
}

static __device__ __forceinline__ void gload_lds16(const void* g, void* l) {
    __builtin_amdgcn_global_load_lds(
        (const __attribute__((address_space(1))) unsigned int*)g,
        (__attribute__((address_space(3))) unsigned int*)l, 16, 0, 0);
}

// Pack W [K=1024][N=640] fp32 -> bf16, MFMA fragment layout:
// frag(kt, ct): lane l, elem e  <=  W[kt*32 + (l>>4)*8 + e][ct*16 + (l&15)]
__global__ void pack_w(const float* __restrict__ W, unsigned short* __restrict__ bp)
{
    const int t = threadIdx.x;
    const int tile = blockIdx.x * 4 + (t >> 6);   // 0..1279 = kt*40+ct
    const int lane = t & 63;
    const int kt = tile / CTN, ct = tile % CTN;
    const int k0 = kt * 32 + (lane >> 4) * 8;
    const int col = ct * 16 + (lane & 15);
    unsigned short v1[8];
    #pragma unroll
    for (int e = 0; e < 8; ++e)
        v1[e] = f2bf(W[(size_t)(k0 + e) * EE + col]);
    *(short8*)(bp + ((size_t)tile * 64 + lane) * 8) = *(const short8*)v1;
}

// ============================ SPLIT PATH ============================
// K1a: pure GEMM. 256 blocks x 1024 threads. Writes bf16 logits z[N][640].
__global__ __launch_bounds__(1024, 4) void gemm_z_kernel(
    const float* __restrict__ x, const unsigned short* __restrict__ bp,
    const float* __restrict__ bias, unsigned short* __restrict__ z)
{
    __shared__ unsigned short Bs[3][32 * EE];     // 3 x 40 KB ring
    __shared__ unsigned short As[2][BM * 32];     // 2 x 8 KB

    const int t    = threadIdx.x;
    const int lane = t & 63;
    const int w    = t >> 6;            // 0..15
    const int rg   = w >> 3;            // 64-row half
    const int cg   = w & 7;             // 80-col group
    const int n0   = blockIdx.x * BM;

    float4v acc[4][5];
    #pragma unroll
    for (int rf = 0; rf < 4; ++rf)
        #pragma unroll
        for (int ct = 0; ct < 5; ++ct)
            acc[rf][ct] = (float4v)0.f;

    const int r0 = t >> 3, kq0 = t & 7;
    const int abase = (r0 >> 4)*512 + ((r0 & 15) + ((kq0 >> 1) << 4))*8 + ((kq0 & 1) << 2);
    const float* xr = x + (size_t)(n0 + r0) * DD + kq0 * 4;

    auto writeA = [&](int bb, float4 v) {
        short4v s1;
        s1[0] = (short)f2bf(v.x); s1[1] = (short)f2bf(v.y);
        s1[2] = (short)f2bf(v.z); s1[3] = (short)f2bf(v.w);
        *(short4v*)&As[bb][abase] = s1;
    };
    const int q0 = t, q1 = t + 1024, q2 = (t < 512) ? t + 2048 : t + 1536;
    auto stageB = [&](int bb, int kt) {
        const unsigned short* src = bp + (size_t)kt * (32 * EE);
        gload_lds16(src + (size_t)q0 * 8, &Bs[bb][q0 * 8]);
        gload_lds16(src + (size_t)q1 * 8, &Bs[bb][q1 * 8]);
        gload_lds16(src + (size_t)q2 * 8, &Bs[bb][q2 * 8]);
    };

    auto kbody = [&](int i, int b0, int bstg, float4& curA, float4& nxtA) {
        asm volatile("s_waitcnt vmcnt(4) lgkmcnt(0)" ::: "memory");
        __builtin_amdgcn_s_barrier();
        __builtin_amdgcn_sched_barrier(0);
        if (i + 2 < KT) {
            stageB(bstg, i + 2);
            nxtA = *(const float4*)(xr + (size_t)(i + 2) * 32);
        }
        __builtin_amdgcn_sched_barrier(0);
        short8 af[4];
        #pragma unroll
        for (int rf = 0; rf < 4; ++rf)
            af[rf] = *(const short8*)&As[i & 1][(rg*4 + rf)*512 + lane*8];
        #pragma unroll
        for (int ct = 0; ct < 5; ++ct) {
            short8 bf = *(const short8*)&Bs[b0][((cg*5 + ct)*64 + lane)*8];
            #pragma unroll
            for (int rf = 0; rf < 4; ++rf)
                acc[rf][ct] = __builtin_amdgcn_mfma_f32_16x16x32_bf16(af[rf], bf, acc[rf][ct], 0, 0, 0);
        }
        __builtin_amdgcn_sched_barrier(0);
        if (i + 1 < KT) writeA((i + 1) & 1, curA);
    };

    float4 pA0, pA1;
    {
        stageB(0, 0);
        float4 a00 = *(const float4*)(xr);
        stageB(1, 1);
        pA0 = *(const float4*)(xr + 32);
        __builtin_amdgcn_sched_barrier(0);
        writeA(0, a00);
    }

    int bc = 0;
    for (int i = 0; i < KT; i += 2) {
        const int b1 = (bc + 1 > 2) ? 0 : bc + 1;
        const int b2 = (bc + 2 > 2) ? bc - 1 : bc + 2;
        kbody(i,     bc, b2, pA0, pA1);
        kbody(i + 1, b1, bc, pA1, pA0);
        bc = b2;
    }

    // epilogue: bias + bf16 z store (col = (cg>>2)*320 + (cg&3)*80 + (lane&15) + ct*16)
    float bv[5];
    const int cbase = (cg >> 2)*320 + (cg & 3)*80 + (lane & 15);
    #pragma unroll
    for (int ct = 0; ct < 5; ++ct) bv[ct] = bias[cbase + ct*16];
    #pragma unroll
    for (int rf = 0; rf < 4; ++rf) {
        #pragma unroll
        for (int r = 0; r < 4; ++r) {
            const size_t n = (size_t)(n0 + rg*64 + rf*16 + ((lane >> 4) << 2) + r);
            #pragma unroll
            for (int ct = 0; ct < 5; ++ct)
                z[n*EE + cbase + ct*16] = f2bf(acc[rf][ct][r] + bv[ct]);
        }
    }
}

// K1b: epilogue. 2048 blocks x 256 threads; block = 16 rows.
// Thread: row = t>>4, 40 contiguous cols at (t&15)*40. Vectorized loads.
__global__ __launch_bounds__(256, 4) void epi_kernel(
    const unsigned short* __restrict__ z, const float* __restrict__ gum,
    const float* __restrict__ cb, float* __restrict__ out,
    float* __restrict__ probs_rep)
{
    __shared__ float probs_blk[EE];
    __shared__ int   sidx[16][2];

    const int t   = threadIdx.x;
    const int row = t >> 4;
    const int cgi = t & 15;
    const size_t n = (size_t)blockIdx.x * 16 + row;
    const int g = cgi >> 3;
    const int vbase = (cgi & 7) * 40;

    for (int c = t; c < EE; c += 256) probs_blk[c] = 0.f;

    uint4 zp[5];
    const uint4* zsrc = (const uint4*)(z + n*EE + cgi*40);
    #pragma unroll
    for (int i = 0; i < 5; ++i) zp[i] = zsrc[i];
    float gv[40];
    const float4* gsrc = (const float4*)(gum + ((n << 1) + g)*VV + vbase);
    #pragma unroll
    for (int i = 0; i < 10; ++i) {
        float4 v = gsrc[i];
        gv[4*i] = v.x; gv[4*i+1] = v.y; gv[4*i+2] = v.z; gv[4*i+3] = v.w;
    }

    float m1 = -1e30f; int bi = 0; float es = 0.f;
    #pragma unroll
    for (int j = 0; j < 40; ++j) {
        const unsigned int u = ((const unsigned int*)zp)[j >> 1];
        const float zj = __uint_as_float((j & 1) ? (u & 0xffff0000u) : (u << 16));
        const float zg = zj + gv[j];
        if (zg > m1) { m1 = zg; bi = vbase + j; }   // ascending j: > keeps first
        es += __expf(zj);
    }
    #pragma unroll
    for (int off = 1; off < 8; off <<= 1) {          // stays within 8-lane half
        float om = __shfl_xor(m1, off);
        int   ob = __shfl_xor(bi, off);
        if (om > m1 || (om == m1 && ob < bi)) { m1 = om; bi = ob; }
        es += __shfl_xor(es, off);
    }
    const float inv = 1.f / es;
    if ((cgi & 7) == 0) sidx[row][g] = bi;
    __syncthreads();

    #pragma unroll
    for (int j = 0; j < 40; ++j) {
        const unsigned int u = ((const unsigned int*)zp)[j >> 1];
        const float zj = __uint_as_float((j & 1) ? (u & 0xffff0000u) : (u << 16));
        atomicAdd(&probs_blk[g*VV + vbase + j], __expf(zj) * inv);
    }

    // gather + out-write: iter k writes row k (4 KB coalesced)
    #pragma unroll 4
    for (int k = 0; k < 16; ++k) {
        const int gg  = t >> 7;
        const int idx = sidx[k][gg];
        const float4 v = *(const float4*)&cb[((size_t)gg*VV + idx)*512 + (size_t)(t & 127)*4];
        *(float4*)&out[((size_t)blockIdx.x*16 + k)*DD + (size_t)t*4] = v;
    }
    __syncthreads();

    const int rep = blockIdx.x & 7;
    for (int c = t; c < EE; c += 256)
        atomicAdd(&probs_rep[rep*EE + c], probs_blk[c]);
}

// ============================ FUSED FALLBACK (R8) ============================
__global__ __launch_bounds__(1024, 4) void logits_kernel(
    const float* __restrict__ x, const unsigned short* __restrict__ bp,
    const float* __restrict__ bias, const float* __restrict__ gum,
    int* __restrict__ gfidx, float* __restrict__ probs_acc)
{
    __shared__ unsigned short Bs[3][32 * EE];
    __shared__ unsigned short As[2][BM * 32];
    __shared__ float probs_blk[EE];
    __shared__ float pmax[8][BM];
    __shared__ float psum[8][BM];
    __shared__ int   pidx[8][BM];
    __shared__ float finv[BM][2];

    const int t    = threadIdx.x;
    const int lane = t & 63;
    const int w    = t >> 6;
    const int rg   = w >> 3;
    const int cg   = w & 7;
    const int n0   = blockIdx.x * BM;

    float4v acc[4][5];
    #pragma unroll
    for (int rf = 0; rf < 4; ++rf)
        #pragma unroll
        for (int ct = 0; ct < 5; ++ct)
            acc[rf][ct] = (float4v)0.f;

    const int r0 = t >> 3, kq0 = t & 7;
    const int abase = (r0 >> 4)*512 + ((r0 & 15) + ((kq0 >> 1) << 4))*8 + ((kq0 & 1) << 2);
    const float* xr = x + (size_t)(n0 + r0) * DD + kq0 * 4;

    auto writeA = [&](int bb, float4 v) {
        short4v s1;
        s1[0] = (short)f2bf(v.x); s1[1] = (short)f2bf(v.y);
        s1[2] = (short)f2bf(v.z); s1[3] = (short)f2bf(v.w);
        *(short4v*)&As[bb][abase] = s1;
    };
    const int q0 = t, q1 = t + 1024, q2 = (t < 512) ? t + 2048 : t + 1536;
    auto stageB = [&](int bb, int kt) {
        const unsigned short* src = bp + (size_t)kt * (32 * EE);
        gload_lds16(src + (size_t)q0 * 8, &Bs[bb][q0 * 8]);
        gload_lds16(src + (size_t)q1 * 8, &Bs[bb][q1 * 8]);
        gload_lds16(src + (size_t)q2 * 8, &Bs[bb][q2 * 8]);
    };
    auto kbody = [&](int i, int b0, int bstg, float4& curA, float4& nxtA) {
        asm volatile("s_waitcnt vmcnt(4) lgkmcnt(0)" ::: "memory");
        __builtin_amdgcn_s_barrier();
        __builtin_amdgcn_sched_barrier(0);
        if (i + 2 < KT) {
            stageB(bstg, i + 2);
            nxtA = *(const float4*)(xr + (size_t)(i + 2) * 32);
        }
        __builtin_amdgcn_sched_barrier(0);
        short8 af[4];
        #pragma unroll
        for (int rf = 0; rf < 4; ++rf)
            af[rf] = *(const short8*)&As[i & 1][(rg*4 + rf)*512 + lane*8];
        #pragma unroll
        for (int ct = 0; ct < 5; ++ct) {
            short8 bf = *(const short8*)&Bs[b0][((cg*5 + ct)*64 + lane)*8];
            #pragma unroll
            for (int rf = 0; rf < 4; ++rf)
                acc[rf][ct] = __builtin_amdgcn_mfma_f32_16x16x32_bf16(af[rf], bf, acc[rf][ct], 0, 0, 0);
        }
        __builtin_amdgcn_sched_barrier(0);
        if (i + 1 < KT) writeA((i + 1) & 1, curA);
    };

    float4 pA0, pA1;
    {
        stageB(0, 0);
        float4 a00 = *(const float4*)(xr);
        stageB(1, 1);
        pA0 = *(const float4*)(xr + 32);
        __builtin_amdgcn_sched_barrier(0);
        writeA(0, a00);
    }
    int bc = 0;
    for (int i = 0; i < KT; i += 2) {
        const int b1 = (bc + 1 > 2) ? 0 : bc + 1;
        const int b2 = (bc + 2 > 2) ? bc - 1 : bc + 2;
        kbody(i,     bc, b2, pA0, pA1);
        kbody(i + 1, b1, bc, pA1, pA0);
        bc = b2;
    }

    {
        float bv[5];
        #pragma unroll
        for (int ct = 0; ct < 5; ++ct) bv[ct] = bias[cg*80 + ct*16 + (lane & 15)];
        #pragma unroll
        for (int rf = 0; rf < 4; ++rf)
            #pragma unroll
            for (int ct = 0; ct < 5; ++ct) {
                acc[rf][ct][0] += bv[ct]; acc[rf][ct][1] += bv[ct];
                acc[rf][ct][2] += bv[ct]; acc[rf][ct][3] += bv[ct];
            }
    }

    const int g = cg >> 2;
    const int goff0 = (cg & 3)*80 + (lane & 15);
    #pragma unroll
    for (int rf = 0; rf < 4; ++rf) {
        #pragma unroll
        for (int r = 0; r < 4; ++r) {
            const int rowA = rg*64 + rf*16 + ((lane >> 4) << 2) + r;
            const float* grow = gum + ((size_t)(n0 + rowA)*2 + g)*VV + goff0;
            float m1 = -1e30f; int bi = 0; float es = 0.f;
            #pragma unroll
            for (int ct = 0; ct < 5; ++ct) {
                float zv  = acc[rf][ct][r];
                float zg = zv + grow[ct*16];
                if (zg > m1) { m1 = zg; bi = goff0 + ct*16; }
                es += __expf(zv);
            }
            #pragma unroll
            for (int off = 1; off < 16; off <<= 1) {
                float om = __shfl_xor(m1, off);
                int   ob = __shfl_xor(bi, off);
                if (om > m1 || (om == m1 && ob < bi)) { m1 = om; bi = ob; }
                es += __shfl_xor(es, off);
            }
            if ((lane & 15) == 0) {
                pmax[cg][rowA] = m1; pidx[cg][rowA] = bi; psum[cg][rowA] = es;
            }
        }
    }
    for (int c = t; c < EE; c += 1024) probs_blk[c] = 0.f;
    __syncthreads();

    if (t < 256) {
        const int row = t & 127, gg = t >> 7;
        float m1 = -1e30f; int bi = 0x7fffffff; float s = 0.f;
        #pragma unroll
        for (int c = 0; c < 4; ++c) {
            const float om = pmax[gg*4 + c][row];
            const int   ob = pidx[gg*4 + c][row];
            if (om > m1 || (om == m1 && ob < bi)) { m1 = om; bi = ob; }
            s += psum[gg*4 + c][row];
        }
        gfidx[(size_t)(n0 + row)*2 + gg] = bi;
        finv[row][gg] = 1.f / s;
    }
    __syncthreads();

    float pacc[5];
    #pragma unroll
    for (int ct = 0; ct < 5; ++ct) pacc[ct] = 0.f;
    #pragma unroll
    for (int rf = 0; rf < 4; ++rf) {
        #pragma unroll
        for (int r = 0; r < 4; ++r) {
            const int rowA = rg*64 + rf*16 + ((lane >> 4) << 2) + r;
            const float inv = finv[rowA][g];
            #pragma unroll
            for (int ct = 0; ct < 5; ++ct)
                pacc[ct] += __expf(acc[rf][ct][r]) * inv;
        }
    }
    #pragma unroll
    for (int off = 16; off < 64; off <<= 1)
        #pragma unroll
        for (int ct = 0; ct < 5; ++ct)
            pacc[ct] += __shfl_xor(pacc[ct], off);
    if (lane < 16) {
        #pragma unroll
        for (int ct = 0; ct < 5; ++ct)
            atomicAdd(&probs_blk[cg*80 + ct*16 + lane], pacc[ct]);
    }
    __syncthreads();
    for (int c = t; c < EE; c += 1024)
        atomicAdd(&probs_acc[c], probs_blk[c]);
}

__global__ __launch_bounds__(256) void gather_kernel(
    const float* __restrict__ cb, const int* __restrict__ gfidx,
    float* __restrict__ out)
{
    __shared__ int sidx[8][2];
    const int t  = threadIdx.x;
    const int r0 = blockIdx.x * 8;
    if (t < 16) sidx[t >> 1][t & 1] = gfidx[(size_t)(r0 + (t >> 1)) * 2 + (t & 1)];
    __syncthreads();
    const int gg = t >> 7;
    #pragma unroll
    for (int r = 0; r < 8; ++r) {
        const int idx = sidx[r][gg];
        const float4 v = *(const float4*)&cb[((size_t)gg*VV + idx)*512 + (size_t)(t & 127)*4];
        *(float4*)&out[(size_t)(r0 + r)*DD + (size_t)t*4] = v;
    }
}

// perplexity from 8-replica probs accumulator
__global__ void perp8_kernel(const float* __restrict__ probs_rep,
                             float* __restrict__ outp)
{
    __shared__ float s0[4], s1[4];
    int t = threadIdx.x;   // 256
    float p0 = 0.f, p1 = 0.f;
    for (int c = t; c < EE; c += 256) {
        float a = 0.f;
        #pragma unroll
        for (int rp = 0; rp < 8; ++rp) a += probs_rep[rp*EE + c];
        a *= (1.0f / NROWS);
        float v = a * logf(a + 1e-7f);
        if (c < VV) p0 += v; else p1 += v;
    }
    #pragma unroll
    for (int off = 1; off < 64; off <<= 1) {
        p0 += __shfl_xor(p0, off);
        p1 += __shfl_xor(p1, off);
    }
    if ((t & 63) == 0) { s0[t >> 6] = p0; s1[t >> 6] = p1; }
    __syncthreads();
    if (t == 0) {
        float a0 = s0[0] + s0[1] + s0[2] + s0[3];
        float a1 = s1[0] + s1[1] + s1[2] + s1[3];
        outp[0] = 0.5f * (expf(-a0) + expf(-a1));
    }
}

extern "C" void kernel_launch(void* const* d_in, const int* in_sizes, int n_in,
                              void* d_out, int out_size, void* d_ws, size_t ws_size,
                              hipStream_t stream)
{
    const float* x   = (const float*)d_in[0];
    const float* W   = (const float*)d_in[1];
    const float* b   = (const float*)d_in[2];
    const float* cb  = (const float*)d_in[3];
    const float* gum = (const float*)d_in[4];
    float* out = (float*)d_out;

    // ws layout: [bp 1.31MB][probs_rep 20KB][gfidx 256KB][z 41.9MB]
    char* wsp = (char*)d_ws;
    unsigned short* bp = (unsigned short*)wsp;
    const size_t bp_b = (size_t)DD*EE*2;
    float* probs_rep = (float*)(wsp + bp_b);
    const size_t pr_b = 8*EE*sizeof(float);
    int* gfidx = (int*)(wsp + bp_b + pr_b);
    const size_t gi_b = (size_t)NROWS*2*sizeof(int);
    unsigned short* z = (unsigned short*)(wsp + bp_b + pr_b + gi_b);
    const size_t need = bp_b + pr_b + gi_b + (size_t)NROWS*EE*2;

    hipMemsetAsync(probs_rep, 0, pr_b, stream);
    pack_w<<<320, 256, 0, stream>>>(W, bp);
    if (ws_size >= need) {
        gemm_z_kernel<<<NROWS / BM, 1024, 0, stream>>>(x, bp, b, z);
        epi_kernel<<<NROWS / 16, 256, 0, stream>>>(z, gum, cb, out, probs_rep);
    } else {
        logits_kernel<<<NROWS / BM, 1024, 0, stream>>>(x, bp, b, gum, gfidx, probs_rep);
        gather_kernel<<<NROWS / 8, 256, 0, stream>>>(cb, gfidx, out);
    }
    perp8_kernel<<<1, 256, 0, stream>>>(probs_rep, out + (out_size - 1));
}